// Round 16
// baseline (354.584 us; speedup 1.0000x reference)
//
#include <hip/hip_runtime.h>
#include <hip/hip_bf16.h>

typedef unsigned short u16;
typedef unsigned int   u32;
typedef __bf16 bf16x8 __attribute__((ext_vector_type(8)));
typedef float  f32x4  __attribute__((ext_vector_type(4)));
typedef u32    u32x4  __attribute__((ext_vector_type(4)));
typedef u32    u32x2  __attribute__((ext_vector_type(2)));

#define TRI_TOTAL 131328  // sum_{n=0}^{511} (n+1)

__device__ __forceinline__ float b2f(u16 u) {
    return __builtin_bit_cast(float, ((u32)u) << 16);
}
// RNE f32->bf16 via compiler intrinsic (emits v_cvt_pk_bf16_f32 for pairs)
__device__ __forceinline__ u16 f2b(float f) {
    return __builtin_bit_cast(u16, __float2bfloat16(f));
}
// Wl swizzle: <=2-way (free) for k-fast reads and col-fast writes
__device__ __forceinline__ int pcol(int col) {
    return (((col & 7) ^ ((col >> 3) & 7)) << 4);
}

// ---------------- LayerNorm -> xn (bf16) ----------------
__global__ void __launch_bounds__(256) ln_kernel(const float* __restrict__ x,
                                                 const float* __restrict__ g,
                                                 const float* __restrict__ b,
                                                 u16* __restrict__ xn) {
    int n = blockIdx.x, t = threadIdx.x;
    float v = x[n * 256 + t];
    __shared__ float red[4];
    float s = v;
    #pragma unroll
    for (int o = 32; o >= 1; o >>= 1) s += __shfl_xor(s, o);
    if ((t & 63) == 0) red[t >> 6] = s;
    __syncthreads();
    float mu = (red[0] + red[1] + red[2] + red[3]) * (1.0f / 256.0f);
    float d = v - mu;
    __syncthreads();
    float s2 = d * d;
    #pragma unroll
    for (int o = 32; o >= 1; o >>= 1) s2 += __shfl_xor(s2, o);
    if ((t & 63) == 0) red[t >> 6] = s2;
    __syncthreads();
    float var = (red[0] + red[1] + red[2] + red[3]) * (1.0f / 256.0f);
    float y = d * rsqrtf(var + 1e-5f) * g[t] + b[t];
    xn[n * 256 + t] = f2b(y);
}

// ---------------- Per-relative-index projections (v16) ----------------
// Q/V: qd[r,m] = xn[m] @ W[r], needed m in [0, 512-r).  Stored at tri(r+m)+m.
// K:   kd[r,pos] = xn[pos] @ Wk[r], needed pos in [511-r, 512).
//      Stored at tri(pos) + (pos-(511-r)).
// v16: LDS = Wl only (32 KB -> 5 blocks/CU, 20 waves). After the one-time
// W-stage + B-frag extraction (16 named regs/wave), the m-loop has NO
// barriers and NO LDS ops: per k-step 2 L2 loads (xn is 256 KB, L2-resident)
// + 4 MFMA, free-running. Five staggered blocks/CU keep the W HBM stream
// busy ~2.5x more of the time than the 2-block v15 (the measured limiter).
__global__ void __launch_bounds__(256) proj_kernel(
        const u16* __restrict__ xn,
        const float* __restrict__ Wq, const float* __restrict__ Wk,
        const float* __restrict__ Wv,
        u16* __restrict__ Qa, u16* __restrict__ Ka, u16* __restrict__ Va) {
    __shared__ u16 Wl[64 * 256];    // 32 KB, [col][k] bf16, pcol-swizzled

    int bid = blockIdx.x;
    int which = bid >> 11;          // 0=Q,1=K,2=V (2048 blocks each)
    int rr = bid & 2047;
    int r  = (which == 1) ? (511 - (rr >> 2)) : (rr >> 2);  // heavy first
    int cs = rr & 3;
    const float* W = (which == 0) ? Wq : ((which == 1) ? Wk : Wv);
    u16* Out       = (which == 0) ? Qa : ((which == 1) ? Ka : Va);
    int rows  = (which == 1) ? (r + 1) : (512 - r);
    int pbase = (which == 1) ? (511 - r) : 0;   // xn position = pbase + ml
    int nbase = (which == 1) ? (511 - r) : r;   // attn row n = nbase + ml

    int t = threadIdx.x;
    int c0 = cs * 64;
    int wv  = t >> 6;               // 0..3
    int rg  = wv >> 1;              // row-group: rows [rg*32, rg*32+32)
    int cg  = wv & 1;               // col-group: cols [cg*32, cg*32+32)
    int L   = t & 63;
    int l15 = L & 15, l4 = L >> 4;

    // ---- Wl stage: coalesced dwordx4 loads, pcol-swizzled b64 writes ----
    {
        int c4 = (t & 15) * 4;      // 4 consecutive cols
        int kq = t >> 4;            // 0..15 -> k-quad base kq*4 (+64/IT)
        const float* wp = W + ((size_t)r << 16) + c0 + c4 + (size_t)(kq * 4) * 256;
        f32x4 w00 = *(const f32x4*)(wp + 0);
        f32x4 w01 = *(const f32x4*)(wp + 256);
        f32x4 w02 = *(const f32x4*)(wp + 512);
        f32x4 w03 = *(const f32x4*)(wp + 768);
        f32x4 w10 = *(const f32x4*)(wp + 16384 + 0);
        f32x4 w11 = *(const f32x4*)(wp + 16384 + 256);
        f32x4 w12 = *(const f32x4*)(wp + 16384 + 512);
        f32x4 w13 = *(const f32x4*)(wp + 16384 + 768);
        f32x4 w20 = *(const f32x4*)(wp + 32768 + 0);
        f32x4 w21 = *(const f32x4*)(wp + 32768 + 256);
        f32x4 w22 = *(const f32x4*)(wp + 32768 + 512);
        f32x4 w23 = *(const f32x4*)(wp + 32768 + 768);
        f32x4 w30 = *(const f32x4*)(wp + 49152 + 0);
        f32x4 w31 = *(const f32x4*)(wp + 49152 + 256);
        f32x4 w32 = *(const f32x4*)(wp + 49152 + 512);
        f32x4 w33 = *(const f32x4*)(wp + 49152 + 768);
#define WLW(IT, VA, VB, VC, VD) {                                             \
        int kbase2 = (kq * 4 + (IT) * 64) * 2;                                \
        _Pragma("unroll")                                                     \
        for (int i = 0; i < 4; ++i) {                                         \
            int col = c4 + i;                                                 \
            u32 lo = (u32)f2b(VA[i]) | ((u32)f2b(VB[i]) << 16);               \
            u32 hi = (u32)f2b(VC[i]) | ((u32)f2b(VD[i]) << 16);               \
            u32x2 pr; pr[0] = lo; pr[1] = hi;                                 \
            *(u32x2*)((char*)Wl + col * 512 + (kbase2 ^ pcol(col))) = pr;     \
        }                                                                     \
    }
        WLW(0, w00, w01, w02, w03)
        WLW(1, w10, w11, w12, w13)
        WLW(2, w20, w21, w22, w23)
        WLW(3, w30, w31, w32, w33)
#undef WLW
    }
    __syncthreads();                // Wl ready

    // ---- B-frag extraction: 16 named bf16x8 from Wl (then Wl is dead) ----
    bf16x8 b00, b01, b02, b03, b04, b05, b06, b07;
    bf16x8 b10, b11, b12, b13, b14, b15, b16, b17;
#define BEXT(HF, KSI, DST) {                                                  \
    int col = cg * 32 + (HF) * 16 + l15;                                      \
    int kb = (KSI) * 64 + l4 * 16;                                            \
    DST = *(const bf16x8*)((const char*)Wl + col * 512 + (kb ^ pcol(col))); }
    BEXT(0, 0, b00) BEXT(0, 1, b01) BEXT(0, 2, b02) BEXT(0, 3, b03)
    BEXT(0, 4, b04) BEXT(0, 5, b05) BEXT(0, 6, b06) BEXT(0, 7, b07)
    BEXT(1, 0, b10) BEXT(1, 1, b11) BEXT(1, 2, b12) BEXT(1, 3, b13)
    BEXT(1, 4, b14) BEXT(1, 5, b15) BEXT(1, 6, b16) BEXT(1, 7, b17)
#undef BEXT
    // no more barriers, no more LDS ops for the rest of the block

    for (int m0 = 0; m0 < rows; m0 += 64) {
        int mlo = m0 + rg * 32 + l15;
        int g0 = pbase + mlo;       if (g0 > 511) g0 = 511;
        int g1 = pbase + mlo + 16;  if (g1 > 511) g1 = 511;
        const char* s0 = (const char*)xn + (size_t)g0 * 512 + l4 * 16;
        const char* s1 = (const char*)xn + (size_t)g1 * 512 + l4 * 16;

        f32x4 acc00 = {}, acc01 = {}, acc10 = {}, acc11 = {};
#define KS(ks) {                                                              \
        bf16x8 a0 = *(const bf16x8*)(s0 + (ks) * 64);                         \
        bf16x8 a1 = *(const bf16x8*)(s1 + (ks) * 64);                         \
        acc00 = __builtin_amdgcn_mfma_f32_16x16x32_bf16(a0, b0##ks, acc00, 0, 0, 0); \
        acc01 = __builtin_amdgcn_mfma_f32_16x16x32_bf16(a0, b1##ks, acc01, 0, 0, 0); \
        acc10 = __builtin_amdgcn_mfma_f32_16x16x32_bf16(a1, b0##ks, acc10, 0, 0, 0); \
        acc11 = __builtin_amdgcn_mfma_f32_16x16x32_bf16(a1, b1##ks, acc11, 0, 0, 0); \
    }
        KS(0) KS(1) KS(2) KS(3) KS(4) KS(5) KS(6) KS(7)
#undef KS

        // store to packed attention layout
        #pragma unroll
        for (int rf = 0; rf < 2; ++rf) {
            #pragma unroll
            for (int j = 0; j < 4; ++j) {
                int ml = m0 + rg * 32 + rf * 16 + l4 * 4 + j;
                if (ml < rows) {
                    u32 nout = (u32)(nbase + ml);
                    u32 prow = (nout * (nout + 1)) >> 1;
                    u16* op = Out + (size_t)(prow + (u32)ml) * 256
                              + c0 + cg * 32 + l15;
                    f32x4 va = rf ? acc10 : acc00;
                    f32x4 vb = rf ? acc11 : acc01;
                    op[0]  = f2b(va[j]);
                    op[16] = f2b(vb[j]);
                }
            }
        }
    }
}

// ---------------- per-row attention ----------------
// Block = one query row n. Band rows tri(n)..tri(n)+n hold per-pair q,k,v.
__global__ void __launch_bounds__(256) attn_kernel(const u16* __restrict__ Qa,
                                                   const u16* __restrict__ Ka,
                                                   const u16* __restrict__ Va,
                                                   float* __restrict__ ao) {
    int n = blockIdx.x, t = threadIdx.x;
    __shared__ float pbuf[512 * 9];   // [m][h] padded pitch 9
    __shared__ float linv[8];
    int band = n + 1;
    size_t rb = (size_t)(n * (n + 1) / 2);

    // scores: thread = (m-inner, h)
    int h = t & 7, mi = t >> 3;
    for (int m0 = 0; m0 < band; m0 += 32) {
        int m = m0 + mi;
        float d = -1e30f;
        if (m < band) {
            const char* qp = (const char*)Qa + (rb + m) * 512 + h * 64;
            const char* kp = (const char*)Ka + (rb + m) * 512 + h * 64;
            float acc = 0.f;
            #pragma unroll
            for (int cch = 0; cch < 4; ++cch) {
                u32x4 qv = *reinterpret_cast<const u32x4*>(qp + cch * 16);
                u32x4 kv = *reinterpret_cast<const u32x4*>(kp + cch * 16);
                #pragma unroll
                for (int i = 0; i < 4; ++i) {
                    float ql = __builtin_bit_cast(float, qv[i] << 16);
                    float qh = __builtin_bit_cast(float, qv[i] & 0xffff0000u);
                    float kl = __builtin_bit_cast(float, kv[i] << 16);
                    float kh = __builtin_bit_cast(float, kv[i] & 0xffff0000u);
                    acc += ql * kl + qh * kh;
                }
            }
            d = acc * 0.17677669529663687f;  // 1/sqrt(32)
        }
        pbuf[m * 9 + h] = d;
    }
    __syncthreads();

    // softmax per head: wave wv handles heads wv and wv+4
    int wv = t >> 6, L = t & 63;
    for (int s = 0; s < 2; ++s) {
        int hh = wv + s * 4;
        float mx = -1e30f;
        for (int m = L; m < band; m += 64) mx = fmaxf(mx, pbuf[m * 9 + hh]);
        #pragma unroll
        for (int o = 32; o >= 1; o >>= 1) mx = fmaxf(mx, __shfl_xor(mx, o));
        float sum = 0.f;
        for (int m = L; m < band; m += 64) {
            float p = __expf(pbuf[m * 9 + hh] - mx);
            pbuf[m * 9 + hh] = p;
            sum += p;
        }
        #pragma unroll
        for (int o = 32; o >= 1; o >>= 1) sum += __shfl_xor(sum, o);
        if (L == 0) linv[hh] = 1.0f / sum;
    }
    __syncthreads();

    // PV: thread = output channel t = h*32+e
    int h2 = t >> 5;
    const char* vp = (const char*)Va + rb * 512 + (size_t)t * 2;
    const float* pb = pbuf + h2;
    float a0 = 0, a1 = 0, a2 = 0, a3 = 0;
    int m = 0;
    for (; m + 4 <= band; m += 4) {
        a0 += pb[(m + 0) * 9] * b2f(*(const u16*)(vp + (size_t)(m + 0) * 512));
        a1 += pb[(m + 1) * 9] * b2f(*(const u16*)(vp + (size_t)(m + 1) * 512));
        a2 += pb[(m + 2) * 9] * b2f(*(const u16*)(vp + (size_t)(m + 2) * 512));
        a3 += pb[(m + 3) * 9] * b2f(*(const u16*)(vp + (size_t)(m + 3) * 512));
    }
    for (; m < band; ++m)
        a0 += pb[m * 9] * b2f(*(const u16*)(vp + (size_t)m * 512));
    ao[n * 256 + t] = ((a0 + a1) + (a2 + a3)) * linv[h2];
}

// ---------------- output projection ----------------
__global__ void __launch_bounds__(256) outproj_kernel(const float* __restrict__ ao,
                                                      const float* __restrict__ Wo,
                                                      const float* __restrict__ bo,
                                                      float* __restrict__ out) {
    int n = blockIdx.x, e = threadIdx.x;
    const float* a = ao + n * 256;
    float c0 = bo[e], c1 = 0, c2 = 0, c3 = 0;
    for (int c = 0; c < 256; c += 4) {
        c0 += a[c + 0] * Wo[(c + 0) * 256 + e];
        c1 += a[c + 1] * Wo[(c + 1) * 256 + e];
        c2 += a[c + 2] * Wo[(c + 2) * 256 + e];
        c3 += a[c + 3] * Wo[(c + 3) * 256 + e];
    }
    out[n * 256 + e] = (c0 + c1) + (c2 + c3);
}

extern "C" void kernel_launch(void* const* d_in, const int* in_sizes, int n_in,
                              void* d_out, int out_size, void* d_ws, size_t ws_size,
                              hipStream_t stream) {
    const float* x     = (const float*)d_in[0];
    const float* Wq    = (const float*)d_in[1];
    const float* Wk    = (const float*)d_in[2];
    const float* Wv    = (const float*)d_in[3];
    const float* gamma = (const float*)d_in[4];
    const float* beta  = (const float*)d_in[5];
    const float* Wo    = (const float*)d_in[6];
    const float* bo    = (const float*)d_in[7];
    float* out = (float*)d_out;

    char* ws = (char*)d_ws;
    u16* xn = (u16*)ws;
    size_t off = (size_t)512 * 256 * 2;
    u16* Qa = (u16*)(ws + off); off += (size_t)TRI_TOTAL * 256 * 2;
    u16* Ka = (u16*)(ws + off); off += (size_t)TRI_TOTAL * 256 * 2;
    u16* Va = (u16*)(ws + off); off += (size_t)TRI_TOTAL * 256 * 2;
    float* ao = (float*)(ws + off);

    ln_kernel<<<512, 256, 0, stream>>>(x, gamma, beta, xn);
    proj_kernel<<<6144, 256, 0, stream>>>(xn, Wq, Wk, Wv, Qa, Ka, Va);
    attn_kernel<<<512, 256, 0, stream>>>(Qa, Ka, Va, ao);
    outproj_kernel<<<512, 256, 0, stream>>>(ao, Wo, bo, out);
}

// Round 17
// 352.369 us; speedup vs baseline: 1.0063x; 1.0063x over previous
//
#include <hip/hip_runtime.h>
#include <hip/hip_bf16.h>

typedef unsigned short u16;
typedef unsigned int   u32;
typedef __bf16 bf16x8 __attribute__((ext_vector_type(8)));
typedef float  f32x4  __attribute__((ext_vector_type(4)));
typedef u32    u32x4  __attribute__((ext_vector_type(4)));
typedef u32    u32x2  __attribute__((ext_vector_type(2)));

#define TRI_TOTAL 131328  // sum_{n=0}^{511} (n+1)

__device__ __forceinline__ float b2f(u16 u) {
    return __builtin_bit_cast(float, ((u32)u) << 16);
}
// RNE f32->bf16 via compiler intrinsic (emits v_cvt_pk_bf16_f32 for pairs)
__device__ __forceinline__ u16 f2b(float f) {
    return __builtin_bit_cast(u16, __float2bfloat16(f));
}
// Wl swizzle: <=2-way (free) for k-fast reads and col-fast writes
__device__ __forceinline__ int pcol(int col) {
    return (((col & 7) ^ ((col >> 3) & 7)) << 4);
}

// ---------------- LayerNorm -> xn (bf16) ----------------
__global__ void __launch_bounds__(256) ln_kernel(const float* __restrict__ x,
                                                 const float* __restrict__ g,
                                                 const float* __restrict__ b,
                                                 u16* __restrict__ xn) {
    int n = blockIdx.x, t = threadIdx.x;
    float v = x[n * 256 + t];
    __shared__ float red[4];
    float s = v;
    #pragma unroll
    for (int o = 32; o >= 1; o >>= 1) s += __shfl_xor(s, o);
    if ((t & 63) == 0) red[t >> 6] = s;
    __syncthreads();
    float mu = (red[0] + red[1] + red[2] + red[3]) * (1.0f / 256.0f);
    float d = v - mu;
    __syncthreads();
    float s2 = d * d;
    #pragma unroll
    for (int o = 32; o >= 1; o >>= 1) s2 += __shfl_xor(s2, o);
    if ((t & 63) == 0) red[t >> 6] = s2;
    __syncthreads();
    float var = (red[0] + red[1] + red[2] + red[3]) * (1.0f / 256.0f);
    float y = d * rsqrtf(var + 1e-5f) * g[t] + b[t];
    xn[n * 256 + t] = f2b(y);
}

// ---------------- Per-relative-index projections (v17) ----------------
// Q/V: qd[r,m] = xn[m] @ W[r], needed m in [0, 512-r).  Stored at tri(r+m)+m.
// K:   kd[r,pos] = xn[pos] @ Wk[r], needed pos in [511-r, 512).
//      Stored at tri(pos) + (pos-(511-r)).
// v17 = v16 + __launch_bounds__(256, 4): VGPR cap 128 (need ~96) so the
// compiler CANNOT chase 8-waves/SIMD occupancy by sinking the 16 B-frags
// back into LDS reads (v16's failure: VGPR=64, BEXT re-rolled into loop).
// 4 blocks/CU x 4 waves: W HBM bursts of 4 staggered blocks interleave
// (R15's limiter was HBM duty cycle at 2 blocks/CU). m-loop: per k-step
// 2 L2 loads + 4 MFMA, no barriers, no LDS ops.
__global__ void __launch_bounds__(256, 4) proj_kernel(
        const u16* __restrict__ xn,
        const float* __restrict__ Wq, const float* __restrict__ Wk,
        const float* __restrict__ Wv,
        u16* __restrict__ Qa, u16* __restrict__ Ka, u16* __restrict__ Va) {
    __shared__ u16 Wl[64 * 256];    // 32 KB, [col][k] bf16, pcol-swizzled

    int bid = blockIdx.x;
    int which = bid >> 11;          // 0=Q,1=K,2=V (2048 blocks each)
    int rr = bid & 2047;
    int r  = (which == 1) ? (511 - (rr >> 2)) : (rr >> 2);  // heavy first
    int cs = rr & 3;
    const float* W = (which == 0) ? Wq : ((which == 1) ? Wk : Wv);
    u16* Out       = (which == 0) ? Qa : ((which == 1) ? Ka : Va);
    int rows  = (which == 1) ? (r + 1) : (512 - r);
    int pbase = (which == 1) ? (511 - r) : 0;   // xn position = pbase + ml
    int nbase = (which == 1) ? (511 - r) : r;   // attn row n = nbase + ml

    int t = threadIdx.x;
    int c0 = cs * 64;
    int wv  = t >> 6;               // 0..3
    int rg  = wv >> 1;              // row-group: rows [rg*32, rg*32+32)
    int cg  = wv & 1;               // col-group: cols [cg*32, cg*32+32)
    int L   = t & 63;
    int l15 = L & 15, l4 = L >> 4;

    // ---- Wl stage: coalesced dwordx4 loads, pcol-swizzled b64 writes ----
    {
        int c4 = (t & 15) * 4;      // 4 consecutive cols
        int kq = t >> 4;            // 0..15 -> k-quad base kq*4 (+64/IT)
        const float* wp = W + ((size_t)r << 16) + c0 + c4 + (size_t)(kq * 4) * 256;
        f32x4 w00 = *(const f32x4*)(wp + 0);
        f32x4 w01 = *(const f32x4*)(wp + 256);
        f32x4 w02 = *(const f32x4*)(wp + 512);
        f32x4 w03 = *(const f32x4*)(wp + 768);
        f32x4 w10 = *(const f32x4*)(wp + 16384 + 0);
        f32x4 w11 = *(const f32x4*)(wp + 16384 + 256);
        f32x4 w12 = *(const f32x4*)(wp + 16384 + 512);
        f32x4 w13 = *(const f32x4*)(wp + 16384 + 768);
        f32x4 w20 = *(const f32x4*)(wp + 32768 + 0);
        f32x4 w21 = *(const f32x4*)(wp + 32768 + 256);
        f32x4 w22 = *(const f32x4*)(wp + 32768 + 512);
        f32x4 w23 = *(const f32x4*)(wp + 32768 + 768);
        f32x4 w30 = *(const f32x4*)(wp + 49152 + 0);
        f32x4 w31 = *(const f32x4*)(wp + 49152 + 256);
        f32x4 w32 = *(const f32x4*)(wp + 49152 + 512);
        f32x4 w33 = *(const f32x4*)(wp + 49152 + 768);
#define WLW(IT, VA, VB, VC, VD) {                                             \
        int kbase2 = (kq * 4 + (IT) * 64) * 2;                                \
        _Pragma("unroll")                                                     \
        for (int i = 0; i < 4; ++i) {                                         \
            int col = c4 + i;                                                 \
            u32 lo = (u32)f2b(VA[i]) | ((u32)f2b(VB[i]) << 16);               \
            u32 hi = (u32)f2b(VC[i]) | ((u32)f2b(VD[i]) << 16);               \
            u32x2 pr; pr[0] = lo; pr[1] = hi;                                 \
            *(u32x2*)((char*)Wl + col * 512 + (kbase2 ^ pcol(col))) = pr;     \
        }                                                                     \
    }
        WLW(0, w00, w01, w02, w03)
        WLW(1, w10, w11, w12, w13)
        WLW(2, w20, w21, w22, w23)
        WLW(3, w30, w31, w32, w33)
#undef WLW
    }
    __syncthreads();                // Wl ready

    // ---- B-frag extraction: 16 named bf16x8 from Wl (then Wl is dead) ----
    bf16x8 b00, b01, b02, b03, b04, b05, b06, b07;
    bf16x8 b10, b11, b12, b13, b14, b15, b16, b17;
#define BEXT(HF, KSI, DST) {                                                  \
    int col = cg * 32 + (HF) * 16 + l15;                                      \
    int kb = (KSI) * 64 + l4 * 16;                                            \
    DST = *(const bf16x8*)((const char*)Wl + col * 512 + (kb ^ pcol(col))); }
    BEXT(0, 0, b00) BEXT(0, 1, b01) BEXT(0, 2, b02) BEXT(0, 3, b03)
    BEXT(0, 4, b04) BEXT(0, 5, b05) BEXT(0, 6, b06) BEXT(0, 7, b07)
    BEXT(1, 0, b10) BEXT(1, 1, b11) BEXT(1, 2, b12) BEXT(1, 3, b13)
    BEXT(1, 4, b14) BEXT(1, 5, b15) BEXT(1, 6, b16) BEXT(1, 7, b17)
#undef BEXT
    // no more barriers, no more LDS ops for the rest of the block

    for (int m0 = 0; m0 < rows; m0 += 64) {
        int mlo = m0 + rg * 32 + l15;
        int g0 = pbase + mlo;       if (g0 > 511) g0 = 511;
        int g1 = pbase + mlo + 16;  if (g1 > 511) g1 = 511;
        const char* s0 = (const char*)xn + (size_t)g0 * 512 + l4 * 16;
        const char* s1 = (const char*)xn + (size_t)g1 * 512 + l4 * 16;

        f32x4 acc00 = {}, acc01 = {}, acc10 = {}, acc11 = {};
#define KS(ks) {                                                              \
        bf16x8 a0 = *(const bf16x8*)(s0 + (ks) * 64);                         \
        bf16x8 a1 = *(const bf16x8*)(s1 + (ks) * 64);                         \
        acc00 = __builtin_amdgcn_mfma_f32_16x16x32_bf16(a0, b0##ks, acc00, 0, 0, 0); \
        acc01 = __builtin_amdgcn_mfma_f32_16x16x32_bf16(a0, b1##ks, acc01, 0, 0, 0); \
        acc10 = __builtin_amdgcn_mfma_f32_16x16x32_bf16(a1, b0##ks, acc10, 0, 0, 0); \
        acc11 = __builtin_amdgcn_mfma_f32_16x16x32_bf16(a1, b1##ks, acc11, 0, 0, 0); \
    }
        KS(0) KS(1) KS(2) KS(3) KS(4) KS(5) KS(6) KS(7)
#undef KS

        // store to packed attention layout
        #pragma unroll
        for (int rf = 0; rf < 2; ++rf) {
            #pragma unroll
            for (int j = 0; j < 4; ++j) {
                int ml = m0 + rg * 32 + rf * 16 + l4 * 4 + j;
                if (ml < rows) {
                    u32 nout = (u32)(nbase + ml);
                    u32 prow = (nout * (nout + 1)) >> 1;
                    u16* op = Out + (size_t)(prow + (u32)ml) * 256
                              + c0 + cg * 32 + l15;
                    f32x4 va = rf ? acc10 : acc00;
                    f32x4 vb = rf ? acc11 : acc01;
                    op[0]  = f2b(va[j]);
                    op[16] = f2b(vb[j]);
                }
            }
        }
    }
}

// ---------------- per-row attention ----------------
// Block = one query row n. Band rows tri(n)..tri(n)+n hold per-pair q,k,v.
__global__ void __launch_bounds__(256) attn_kernel(const u16* __restrict__ Qa,
                                                   const u16* __restrict__ Ka,
                                                   const u16* __restrict__ Va,
                                                   float* __restrict__ ao) {
    int n = blockIdx.x, t = threadIdx.x;
    __shared__ float pbuf[512 * 9];   // [m][h] padded pitch 9
    __shared__ float linv[8];
    int band = n + 1;
    size_t rb = (size_t)(n * (n + 1) / 2);

    // scores: thread = (m-inner, h)
    int h = t & 7, mi = t >> 3;
    for (int m0 = 0; m0 < band; m0 += 32) {
        int m = m0 + mi;
        float d = -1e30f;
        if (m < band) {
            const char* qp = (const char*)Qa + (rb + m) * 512 + h * 64;
            const char* kp = (const char*)Ka + (rb + m) * 512 + h * 64;
            float acc = 0.f;
            #pragma unroll
            for (int cch = 0; cch < 4; ++cch) {
                u32x4 qv = *reinterpret_cast<const u32x4*>(qp + cch * 16);
                u32x4 kv = *reinterpret_cast<const u32x4*>(kp + cch * 16);
                #pragma unroll
                for (int i = 0; i < 4; ++i) {
                    float ql = __builtin_bit_cast(float, qv[i] << 16);
                    float qh = __builtin_bit_cast(float, qv[i] & 0xffff0000u);
                    float kl = __builtin_bit_cast(float, kv[i] << 16);
                    float kh = __builtin_bit_cast(float, kv[i] & 0xffff0000u);
                    acc += ql * kl + qh * kh;
                }
            }
            d = acc * 0.17677669529663687f;  // 1/sqrt(32)
        }
        pbuf[m * 9 + h] = d;
    }
    __syncthreads();

    // softmax per head: wave wv handles heads wv and wv+4
    int wv = t >> 6, L = t & 63;
    for (int s = 0; s < 2; ++s) {
        int hh = wv + s * 4;
        float mx = -1e30f;
        for (int m = L; m < band; m += 64) mx = fmaxf(mx, pbuf[m * 9 + hh]);
        #pragma unroll
        for (int o = 32; o >= 1; o >>= 1) mx = fmaxf(mx, __shfl_xor(mx, o));
        float sum = 0.f;
        for (int m = L; m < band; m += 64) {
            float p = __expf(pbuf[m * 9 + hh] - mx);
            pbuf[m * 9 + hh] = p;
            sum += p;
        }
        #pragma unroll
        for (int o = 32; o >= 1; o >>= 1) sum += __shfl_xor(sum, o);
        if (L == 0) linv[hh] = 1.0f / sum;
    }
    __syncthreads();

    // PV: thread = output channel t = h*32+e
    int h2 = t >> 5;
    const char* vp = (const char*)Va + rb * 512 + (size_t)t * 2;
    const float* pb = pbuf + h2;
    float a0 = 0, a1 = 0, a2 = 0, a3 = 0;
    int m = 0;
    for (; m + 4 <= band; m += 4) {
        a0 += pb[(m + 0) * 9] * b2f(*(const u16*)(vp + (size_t)(m + 0) * 512));
        a1 += pb[(m + 1) * 9] * b2f(*(const u16*)(vp + (size_t)(m + 1) * 512));
        a2 += pb[(m + 2) * 9] * b2f(*(const u16*)(vp + (size_t)(m + 2) * 512));
        a3 += pb[(m + 3) * 9] * b2f(*(const u16*)(vp + (size_t)(m + 3) * 512));
    }
    for (; m < band; ++m)
        a0 += pb[m * 9] * b2f(*(const u16*)(vp + (size_t)m * 512));
    ao[n * 256 + t] = ((a0 + a1) + (a2 + a3)) * linv[h2];
}

// ---------------- output projection ----------------
__global__ void __launch_bounds__(256) outproj_kernel(const float* __restrict__ ao,
                                                      const float* __restrict__ Wo,
                                                      const float* __restrict__ bo,
                                                      float* __restrict__ out) {
    int n = blockIdx.x, e = threadIdx.x;
    const float* a = ao + n * 256;
    float c0 = bo[e], c1 = 0, c2 = 0, c3 = 0;
    for (int c = 0; c < 256; c += 4) {
        c0 += a[c + 0] * Wo[(c + 0) * 256 + e];
        c1 += a[c + 1] * Wo[(c + 1) * 256 + e];
        c2 += a[c + 2] * Wo[(c + 2) * 256 + e];
        c3 += a[c + 3] * Wo[(c + 3) * 256 + e];
    }
    out[n * 256 + e] = (c0 + c1) + (c2 + c3);
}

extern "C" void kernel_launch(void* const* d_in, const int* in_sizes, int n_in,
                              void* d_out, int out_size, void* d_ws, size_t ws_size,
                              hipStream_t stream) {
    const float* x     = (const float*)d_in[0];
    const float* Wq    = (const float*)d_in[1];
    const float* Wk    = (const float*)d_in[2];
    const float* Wv    = (const float*)d_in[3];
    const float* gamma = (const float*)d_in[4];
    const float* beta  = (const float*)d_in[5];
    const float* Wo    = (const float*)d_in[6];
    const float* bo    = (const float*)d_in[7];
    float* out = (float*)d_out;

    char* ws = (char*)d_ws;
    u16* xn = (u16*)ws;
    size_t off = (size_t)512 * 256 * 2;
    u16* Qa = (u16*)(ws + off); off += (size_t)TRI_TOTAL * 256 * 2;
    u16* Ka = (u16*)(ws + off); off += (size_t)TRI_TOTAL * 256 * 2;
    u16* Va = (u16*)(ws + off); off += (size_t)TRI_TOTAL * 256 * 2;
    float* ao = (float*)(ws + off);

    ln_kernel<<<512, 256, 0, stream>>>(x, gamma, beta, xn);
    proj_kernel<<<6144, 256, 0, stream>>>(xn, Wq, Wk, Wv, Qa, Ka, Va);
    attn_kernel<<<512, 256, 0, stream>>>(Qa, Ka, Va, ao);
    outproj_kernel<<<512, 256, 0, stream>>>(ao, Wo, bo, out);
}